// Round 7
// baseline (652.379 us; speedup 1.0000x reference)
//
#include <hip/hip_runtime.h>
#include <hip/hip_bf16.h>

typedef __attribute__((ext_vector_type(8))) __bf16 bf16x8;
typedef __attribute__((ext_vector_type(4))) __bf16 bf16x4;
typedef __attribute__((ext_vector_type(4))) float  f32x4;
typedef float f32x4u __attribute__((ext_vector_type(4), aligned(4)));

#define NB 16
#define NS 2048
#define ND 128
#define SCALE 0.08838834764831845f  // 1/sqrt(128)

#define VMW(n) asm volatile("s_waitcnt vmcnt(" #n ")" ::: "memory")
#define SCHED0() __builtin_amdgcn_sched_barrier(0)
#define SBAR()  __builtin_amdgcn_s_barrier()

// ---------------- shared helpers ----------------
__device__ __forceinline__ bf16x8 ld8_256(const __bf16* base, int row, int byteInRow) {
    int off = row * 256 + (byteInRow ^ ((row & 7) << 4));
    return *reinterpret_cast<const bf16x8*>(reinterpret_cast<const char*>(base) + off);
}
__device__ __forceinline__ void glds16(const void* g, void* l) {
    __builtin_amdgcn_global_load_lds(
        (const __attribute__((address_space(1))) unsigned int*)g,
        (__attribute__((address_space(3))) unsigned int*)l, 16, 0, 0);
}

// ---------------- preconversion ----------------
__global__ __launch_bounds__(256) void conv_qk(const float* __restrict__ q,
                                               const float* __restrict__ k,
                                               __bf16* __restrict__ qb,
                                               __bf16* __restrict__ kb) {
    size_t i = (size_t)blockIdx.x * 256 + threadIdx.x;
    const float4* qs = (const float4*)q;
    const float4* ks = (const float4*)k;
    float4 a = qs[2 * i], b = qs[2 * i + 1];
    bf16x8 o;
    o[0] = (__bf16)(a.x * SCALE); o[1] = (__bf16)(a.y * SCALE);
    o[2] = (__bf16)(a.z * SCALE); o[3] = (__bf16)(a.w * SCALE);
    o[4] = (__bf16)(b.x * SCALE); o[5] = (__bf16)(b.y * SCALE);
    o[6] = (__bf16)(b.z * SCALE); o[7] = (__bf16)(b.w * SCALE);
    *(bf16x8*)&qb[i * 8] = o;
    a = ks[2 * i]; b = ks[2 * i + 1];
    o[0] = (__bf16)a.x; o[1] = (__bf16)a.y; o[2] = (__bf16)a.z; o[3] = (__bf16)a.w;
    o[4] = (__bf16)b.x; o[5] = (__bf16)b.y; o[6] = (__bf16)b.z; o[7] = (__bf16)b.w;
    *(bf16x8*)&kb[i * 8] = o;
}

__global__ __launch_bounds__(256) void conv_vt(const float* __restrict__ v,
                                               __bf16* __restrict__ vt) {
    __shared__ __bf16 tile[128 * 128];
    const int b = blockIdx.x >> 4, st = blockIdx.x & 15;
    const int s0 = st * 128, t = threadIdx.x;
    const int rlane = t >> 5, cv = (t & 31) * 4;
    #pragma unroll
    for (int it = 0; it < 16; ++it) {
        int s = rlane + it * 8;
        float4 f = *(const float4*)(v + ((size_t)b * NS + s0 + s) * ND + cv);
        bf16x4 h;
        h[0] = (__bf16)f.x; h[1] = (__bf16)f.y; h[2] = (__bf16)f.z; h[3] = (__bf16)f.w;
        *(bf16x4*)&tile[s * 128 + (cv ^ (s & 60))] = h;
    }
    __syncthreads();
    #pragma unroll
    for (int it = 0; it < 16; ++it) {
        int d = rlane + it * 8;
        bf16x4 o;
        #pragma unroll
        for (int e = 0; e < 4; ++e)
            o[e] = tile[(cv + e) * 128 + (d ^ ((cv + e) & 60))];
        *(bf16x4*)&vt[((size_t)b * ND + d) * NS + s0 + cv] = o;
    }
}

// ---------------- kernel A: per-half (m, sum-exp) + mask bit pack ----------------
// grid 1024: block = (batch b, 64 q-rows, K-half). KT=32, 3-buf, 1 barrier/tile.
__global__ __launch_bounds__(256, 4) void kA_ms(
    const __bf16* __restrict__ qbuf, const __bf16* __restrict__ kbuf,
    const int* __restrict__ mg, unsigned short* __restrict__ bitsg,
    float* __restrict__ msb)
{
    __shared__ __align__(16) char bufs[3][32 * 256];   // 24 KB
    const int bid = blockIdx.x;
    const int lb = (bid & 7) * 128 + (bid >> 3);       // XCD swizzle (1024 wgs)
    const int b = lb >> 6, qblk = (lb >> 1) & 31, kh = lb & 1;
    const int t = threadIdx.x, w = t >> 6, l15 = t & 15, g = (t & 63) >> 4;
    const int qrow = qblk * 64 + w * 16 + l15;
    const size_t grow = (size_t)b * NS + qrow;
    const int kbase = kh * 1024;
    const __bf16* kbB = kbuf + (size_t)b * NS * ND;
    const int* mrow = mg + grow * NS + kbase;

    bf16x8 qf[4];
    {
        const __bf16* qr = qbuf + grow * ND;
        #pragma unroll
        for (int kc = 0; kc < 4; ++kc) qf[kc] = *(const bf16x8*)(qr + kc * 32 + g * 8);
    }
    auto stageK = [&](char* buf, int j) {
        const int k0 = kbase + j * 32;
        #pragma unroll
        for (int i = 0; i < 2; ++i) {
            int c = i * 256 + t, row = c >> 4, pc = c & 15, lc = pc ^ (row & 7);
            glds16(kbB + (size_t)(k0 + row) * ND + lc * 8, buf + c * 16);
        }
    };

    stageK(bufs[0], 0);
    stageK(bufs[1], 1);
    int4 mk[2][2];
    #pragma unroll
    for (int c = 0; c < 2; ++c) mk[0][c] = *(const int4*)(mrow + c * 16 + g * 4);

    float ml = -1e30f, sl = 0.0f;
    unsigned bitsArr[8];
    #pragma unroll
    for (int p = 0; p < 8; ++p) bitsArr[p] = 0u;

    #pragma unroll
    for (int i = 0; i < 32; ++i) {
        // ledger: stageK(i) retired when newest {mask,stage,mask} remain
        if (i == 0 || i == 31) { VMW(4); } else { VMW(6); }
        SCHED0(); SBAR(); SCHED0();
        const __bf16* K = (const __bf16*)bufs[i % 3];
        f32x4 acc[2];
        #pragma unroll
        for (int c = 0; c < 2; ++c) {
            f32x4 z = {0.f, 0.f, 0.f, 0.f}; acc[c] = z;
            #pragma unroll
            for (int kc = 0; kc < 4; ++kc) {
                bf16x8 kf = ld8_256(K, c * 16 + l15, kc * 64 + g * 16);
                acc[c] = __builtin_amdgcn_mfma_f32_16x16x32_bf16(kf, qf[kc], acc[c], 0, 0, 0);
            }
        }
        const int4* mc = mk[i & 1];
        unsigned bits = 0; float mx = -1e30f; float sv[8]; bool onv[8];
        #pragma unroll
        for (int c = 0; c < 2; ++c) {
            int mm[4] = {mc[c].x, mc[c].y, mc[c].z, mc[c].w};
            #pragma unroll
            for (int r = 0; r < 4; ++r) {
                bool on = mm[r] != 0;
                sv[c * 4 + r] = acc[c][r];
                onv[c * 4 + r] = on;
                mx = fmaxf(mx, on ? acc[c][r] : -1e30f);
                bits |= on ? (1u << (c * 4 + r)) : 0u;
            }
        }
        float mnew = fmaxf(ml, mx);
        float corr = __expf(ml - mnew);
        float ps = 0.f;
        #pragma unroll
        for (int q = 0; q < 8; ++q) ps += onv[q] ? __expf(sv[q] - mnew) : 0.f;
        sl = sl * corr + ps;
        ml = mnew;
        bitsArr[i >> 2] |= bits << ((i & 3) * 8);
        if (i + 2 < 32) stageK(bufs[(i + 2) % 3], i + 2);
        if (i + 1 < 32) {
            #pragma unroll
            for (int c = 0; c < 2; ++c)
                mk[(i + 1) & 1][c] = *(const int4*)(mrow + (i + 1) * 32 + c * 16 + g * 4);
        }
    }
    // merge the 4 lanes (g=0..3) sharing this q-row
    #pragma unroll
    for (int d = 16; d <= 32; d <<= 1) {
        float mo = __shfl_xor(ml, d), so = __shfl_xor(sl, d);
        float mn = fmaxf(ml, mo);
        sl = sl * __expf(ml - mn) + so * __expf(mo - mn);
        ml = mn;
    }
    uint4 b0 = {bitsArr[0], bitsArr[1], bitsArr[2], bitsArr[3]};
    uint4 b1 = {bitsArr[4], bitsArr[5], bitsArr[6], bitsArr[7]};
    uint4* bp = (uint4*)(bitsg + (grow * 4 + g) * 32 + kh * 16);
    bp[0] = b0; bp[1] = b1;
    if (g == 0) ((float2*)msb)[grow * 2 + kh] = make_float2(ml, sl);
}

// ---------------- kernel M: merge halves -> (m, inv), sink col ----------------
__global__ __launch_bounds__(256) void kM_merge(const float* __restrict__ msb,
                                                float* __restrict__ minv,
                                                float* __restrict__ pg)
{
    int r = blockIdx.x * 256 + threadIdx.x;     // r < NB*NS
    float4 ms = ((const float4*)msb)[r];        // {m0,s0,m1,s1}
    float m = fmaxf(ms.x, ms.z);
    float s = ms.y * __expf(ms.x - m) + ms.w * __expf(ms.z - m);
    float inv = 1.0f / (1.0f + s);
    ((float2*)minv)[r] = make_float2(m, inv);
    pg[(size_t)r * (NS + 1)] = 0.0f;            // sink column
}

// ---------------- kernel B: p write + partial PV per K-half ----------------
// grid 1024, KT=32, K/V double-buffered, 2 counted barriers per tile.
__global__ __launch_bounds__(256, 4) void kB_pv(
    const __bf16* __restrict__ qbuf, const __bf16* __restrict__ kbuf,
    const __bf16* __restrict__ vtb, const unsigned short* __restrict__ bitsg,
    const float* __restrict__ minv, float* __restrict__ pg,
    float* __restrict__ outp)
{
    __shared__ __align__(16) char Kb[2][32 * 256];     // 16 KB
    __shared__ __align__(16) char Vb[2][128 * 64];     // 16 KB
    __shared__ __align__(16) __bf16 Ps[4][16 * 32];    // 4 KB
    const int bid = blockIdx.x;
    const int lb = (bid & 7) * 128 + (bid >> 3);
    const int b = lb >> 6, qblk = (lb >> 1) & 31, kh = lb & 1;
    const int q0 = qblk * 64;
    const int t = threadIdx.x, w = t >> 6, l15 = t & 15, g = (t & 63) >> 4;
    const int qrow = q0 + w * 16 + l15;
    const size_t grow = (size_t)b * NS + qrow;
    const int kbase = kh * 1024;
    const __bf16* kbB  = kbuf + (size_t)b * NS * ND;
    const __bf16* vtbB = vtb  + (size_t)b * ND * NS;

    float2 mi = ((const float2*)minv)[grow];           // 1 vmem op
    bf16x8 qf[4];
    {
        const __bf16* qr = qbuf + grow * ND;
        #pragma unroll
        for (int kc = 0; kc < 4; ++kc) qf[kc] = *(const bf16x8*)(qr + kc * 32 + g * 8);
    }
    auto stageK = [&](char* buf, int j) {
        const int k0 = kbase + j * 32;
        #pragma unroll
        for (int i = 0; i < 2; ++i) {
            int c = i * 256 + t, row = c >> 4, pc = c & 15, lc = pc ^ (row & 7);
            glds16(kbB + (size_t)(k0 + row) * ND + lc * 8, buf + c * 16);
        }
    };
    auto stageV = [&](char* buf, int j) {
        const int k0 = kbase + j * 32;
        #pragma unroll
        for (int i = 0; i < 2; ++i) {
            int c = i * 256 + t, d = c >> 2, pc = c & 3;
            glds16(vtbB + (size_t)d * NS + k0 + pc * 8, buf + c * 16);
        }
    };

    f32x4 oacc[8];
    #pragma unroll
    for (int cf = 0; cf < 8; ++cf) { f32x4 z = {0.f, 0.f, 0.f, 0.f}; oacc[cf] = z; }

    stageK(Kb[0], 0);
    stageV(Vb[0], 0);
    const size_t prow = grow * (size_t)(NS + 1);
    const unsigned short* bitp = bitsg + (grow * 4 + g) * 32 + kh * 16;
    __bf16* Psw = Ps[w];

    for (int j = 0; j < 32; ++j) {
        const int k0 = kbase + j * 32;
        if (j < 31) stageK(Kb[(j + 1) & 1], j + 1);
        unsigned bits = *(volatile const unsigned short*)(bitp + (j >> 1));  // 1 op/iter
        // ledger: retire stageK(j)
        if (j == 0)       { VMW(5); }
        else if (j == 31) { VMW(6); }
        else              { VMW(8); }
        SCHED0(); SBAR(); SCHED0();
        const __bf16* K = (const __bf16*)Kb[j & 1];
        f32x4 acc[2];
        #pragma unroll
        for (int c = 0; c < 2; ++c) {
            f32x4 z = {0.f, 0.f, 0.f, 0.f}; acc[c] = z;
            #pragma unroll
            for (int kc = 0; kc < 4; ++kc) {
                bf16x8 kf = ld8_256(K, c * 16 + l15, kc * 64 + g * 16);
                acc[c] = __builtin_amdgcn_mfma_f32_16x16x32_bf16(kf, qf[kc], acc[c], 0, 0, 0);
            }
        }
        const int sh = (j & 1) * 8;
        #pragma unroll
        for (int c = 0; c < 2; ++c) {
            f32x4 pv; bf16x4 pb;
            #pragma unroll
            for (int r = 0; r < 4; ++r) {
                bool on = (bits >> (sh + c * 4 + r)) & 1u;
                float p = on ? __expf(acc[c][r] - mi.x) * mi.y : 0.0f;
                pv[r] = p; pb[r] = (__bf16)p;
            }
            *(f32x4u*)&pg[prow + 1 + k0 + c * 16 + g * 4] = pv;   // 1 store each
            *(bf16x4*)((char*)Psw + l15 * 64 + c * 32 + g * 8) = pb;
        }
        if (j < 31) stageV(Vb[(j + 1) & 1], j + 1);
        // ledger: retire stageV(j)
        if (j == 31) { VMW(3); } else { VMW(7); }
        SCHED0(); SBAR(); SCHED0();
        const char* V = Vb[j & 1];
        bf16x8 af = *(const bf16x8*)((const char*)Psw + l15 * 64 + g * 16);
        #pragma unroll
        for (int cf = 0; cf < 8; ++cf) {
            bf16x8 vf = *(const bf16x8*)(V + (cf * 16 + l15) * 64 + g * 16);
            oacc[cf] = __builtin_amdgcn_mfma_f32_16x16x32_bf16(af, vf, oacc[cf], 0, 0, 0);
        }
    }

    float* op = outp + (size_t)kh * NB * NS * ND;
    #pragma unroll
    for (int cf = 0; cf < 8; ++cf)
        #pragma unroll
        for (int r = 0; r < 4; ++r)
            op[((size_t)b * NS + q0 + w * 16 + g * 4 + r) * ND + cf * 16 + l15] = oacc[cf][r];
}

// ---------------- kernel C: sum the two PV halves ----------------
__global__ __launch_bounds__(256) void kC_add(const float* __restrict__ outp,
                                              float* __restrict__ outg)
{
    size_t i = (size_t)blockIdx.x * 256 + threadIdx.x;
    const f32x4* a = (const f32x4*)outp;
    f32x4 r = a[i] + a[i + (size_t)NB * NS * ND / 4];
    ((f32x4*)outg)[i] = r;
}

// ---------------- fallback (ws too small): round-1 proven kernel ----------------
__device__ __forceinline__ bf16x8 ld8_128(const __bf16* base, int row, int byteInRow) {
    int off = row * 128 + (byteInRow ^ ((row & 7) << 4));
    return *reinterpret_cast<const bf16x8*>(reinterpret_cast<const char*>(base) + off);
}
__device__ __forceinline__ void stage_rm(__bf16* dst, const float* src, int t) {
    int row = t >> 2, cg = t & 3;
    const float4* s4 = reinterpret_cast<const float4*>(src + (size_t)row * ND) + cg * 8;
    #pragma unroll
    for (int j = 0; j < 8; ++j) {
        float4 f = s4[j];
        bf16x4 h;
        h[0] = (__bf16)f.x; h[1] = (__bf16)f.y; h[2] = (__bf16)f.z; h[3] = (__bf16)f.w;
        int off = (cg * 64 + j * 8) ^ ((row & 7) << 4);
        *reinterpret_cast<bf16x4*>(reinterpret_cast<char*>(dst) + row * 256 + off) = h;
    }
}

__global__ __launch_bounds__(256, 2) void qa_fused_fb(
    const float* __restrict__ qg, const float* __restrict__ kg,
    const float* __restrict__ vg, const int* __restrict__ mg,
    float* __restrict__ outg, float* __restrict__ pg)
{
    __shared__ __bf16 Qs[64 * ND];
    __shared__ __bf16 Ks[64 * ND];
    __shared__ __bf16 Vt[ND * 64];
    __shared__ __bf16 Psf[4 * 16 * 64];
    __shared__ unsigned int bmf[64][64];

    const int bid = blockIdx.x;
    const int lb  = (bid & 7) * 64 + (bid >> 3);
    const int b   = lb >> 5;
    const int q0  = (lb & 31) * 64;
    const int t   = threadIdx.x;
    const int w   = t >> 6;
    const int l   = t & 63;
    const int l15 = l & 15;
    const int g   = l >> 4;

    stage_rm(Qs, qg + ((size_t)b * NS + q0) * ND, t);
    if (t < 64) pg[((size_t)b * NS + q0 + t) * (size_t)(NS + 1)] = 0.0f;
    __syncthreads();

    bf16x8 qf[4];
    const int arow = w * 16 + l15;
    #pragma unroll
    for (int kc = 0; kc < 4; ++kc) qf[kc] = ld8_256(Qs, arow, kc * 64 + g * 16);

    float mrun[4], srun[4];
    #pragma unroll
    for (int r = 0; r < 4; ++r) { mrun[r] = -1e9f; srun[r] = 0.0f; }

    for (int kt = 0; kt < 32; ++kt) {
        const int k0 = kt * 64;
        __syncthreads();
        stage_rm(Ks, kg + ((size_t)b * NS + k0) * ND, t);
        #pragma unroll 4
        for (int i = 0; i < 16; ++i) {
            int row = w * 16 + i;
            int mv = mg[((size_t)b * NS + (q0 + row)) * NS + k0 + l];
            unsigned long long bal = __ballot(mv != 0);
            if (l == 0) {
                bmf[row][2 * kt]     = (unsigned)bal;
                bmf[row][2 * kt + 1] = (unsigned)(bal >> 32);
            }
        }
        __syncthreads();

        f32x4 acc[4];
        #pragma unroll
        for (int c = 0; c < 4; ++c) {
            f32x4 z = {0.f, 0.f, 0.f, 0.f};
            acc[c] = z;
            #pragma unroll
            for (int kc = 0; kc < 4; ++kc) {
                bf16x8 bf = ld8_256(Ks, c * 16 + l15, kc * 64 + g * 16);
                acc[c] = __builtin_amdgcn_mfma_f32_16x16x32_bf16(qf[kc], bf, acc[c], 0, 0, 0);
            }
        }

        #pragma unroll
        for (int r = 0; r < 4; ++r) {
            const int row = w * 16 + g * 4 + r;
            const unsigned w0 = bmf[row][2 * kt], w1 = bmf[row][2 * kt + 1];
            float sv[4], tmax = -1e9f;
            #pragma unroll
            for (int c = 0; c < 4; ++c) {
                int cb = c * 16 + l15;
                unsigned word = (c < 2) ? w0 : w1;
                bool on = (word >> (cb & 31)) & 1u;
                float s = on ? acc[c][r] * SCALE : -1e9f;
                sv[c] = s;
                tmax = fmaxf(tmax, s);
            }
            #pragma unroll
            for (int d = 1; d < 16; d <<= 1) tmax = fmaxf(tmax, __shfl_xor(tmax, d));
            float mnew = fmaxf(mrun[r], tmax);
            float corr = __expf(mrun[r] - mnew);
            float ps = 0.f;
            #pragma unroll
            for (int c = 0; c < 4; ++c) ps += __expf(sv[c] - mnew);
            #pragma unroll
            for (int d = 1; d < 16; d <<= 1) ps += __shfl_xor(ps, d);
            srun[r] = srun[r] * corr + ps;
            mrun[r] = mnew;
        }
    }

    float inv[4];
    #pragma unroll
    for (int r = 0; r < 4; ++r) inv[r] = 1.0f / (1.0f + srun[r]);

    f32x4 oacc[8];
    #pragma unroll
    for (int cf = 0; cf < 8; ++cf) { f32x4 z = {0.f,0.f,0.f,0.f}; oacc[cf] = z; }

    __bf16* Psw = Psf + w * (16 * 64);

    for (int kt = 0; kt < 32; ++kt) {
        const int k0 = kt * 64;
        __syncthreads();
        stage_rm(Ks, kg + ((size_t)b * NS + k0) * ND, t);
        {
            int kk = t >> 2, dg = t & 3;
            const float4* s4 = reinterpret_cast<const float4*>(vg + ((size_t)b * NS + k0 + kk) * ND) + dg * 8;
            #pragma unroll
            for (int j = 0; j < 8; ++j) {
                float4 f = s4[j];
                int d0 = dg * 32 + j * 4;
                float fv[4] = {f.x, f.y, f.z, f.w};
                #pragma unroll
                for (int e = 0; e < 4; ++e) {
                    int d = d0 + e;
                    int off = d * 128 + ((kk * 2) ^ ((d & 7) << 4));
                    *reinterpret_cast<__bf16*>(reinterpret_cast<char*>(Vt) + off) = (__bf16)fv[e];
                }
            }
        }
        __syncthreads();

        f32x4 acc[4];
        #pragma unroll
        for (int c = 0; c < 4; ++c) {
            f32x4 z = {0.f, 0.f, 0.f, 0.f};
            acc[c] = z;
            #pragma unroll
            for (int kc = 0; kc < 4; ++kc) {
                bf16x8 bf = ld8_256(Ks, c * 16 + l15, kc * 64 + g * 16);
                acc[c] = __builtin_amdgcn_mfma_f32_16x16x32_bf16(qf[kc], bf, acc[c], 0, 0, 0);
            }
        }

        #pragma unroll
        for (int r = 0; r < 4; ++r) {
            const int row16 = g * 4 + r;
            const int row = w * 16 + row16;
            const unsigned w0 = bmf[row][2 * kt], w1 = bmf[row][2 * kt + 1];
            const size_t prowf = ((size_t)b * NS + q0 + row) * (size_t)(NS + 1);
            #pragma unroll
            for (int c = 0; c < 4; ++c) {
                int cb = c * 16 + l15;
                unsigned word = (c < 2) ? w0 : w1;
                bool on = (word >> (cb & 31)) & 1u;
                float p = on ? __expf(acc[c][r] * SCALE - mrun[r]) * inv[r] : 0.0f;
                pg[prowf + 1 + k0 + cb] = p;
                int off = row16 * 128 + ((cb * 2) ^ ((row16 & 7) << 4));
                *reinterpret_cast<__bf16*>(reinterpret_cast<char*>(Psw) + off) = (__bf16)p;
            }
        }

        #pragma unroll
        for (int kc = 0; kc < 2; ++kc) {
            bf16x8 af = ld8_128(Psw, l15, kc * 64 + g * 16);
            #pragma unroll
            for (int cf = 0; cf < 8; ++cf) {
                bf16x8 vfr = ld8_128(Vt, cf * 16 + l15, kc * 64 + g * 16);
                oacc[cf] = __builtin_amdgcn_mfma_f32_16x16x32_bf16(af, vfr, oacc[cf], 0, 0, 0);
            }
        }
    }

    #pragma unroll
    for (int cf = 0; cf < 8; ++cf)
        #pragma unroll
        for (int r = 0; r < 4; ++r)
            outg[((size_t)b * NS + q0 + w * 16 + g * 4 + r) * ND + cf * 16 + l15] = oacc[cf][r];
}

extern "C" void kernel_launch(void* const* d_in, const int* in_sizes, int n_in,
                              void* d_out, int out_size, void* d_ws, size_t ws_size,
                              hipStream_t stream) {
    const float* q = (const float*)d_in[0];
    const float* k = (const float*)d_in[1];
    const float* v = (const float*)d_in[2];
    const int*  mk = (const int*)d_in[3];
    float* out = (float*)d_out;
    float* p   = out + (size_t)NB * NS * ND;

    const size_t E = (size_t)NB * NS * ND;              // 4,194,304 elements
    // ws layout (bytes): qb 2E | kb 2E | vt 2E | bits 2E | msb 512K | minv 256K | outp 8E
    const size_t off_qb   = 0;
    const size_t off_kb   = 2 * E;
    const size_t off_vt   = 4 * E;
    const size_t off_bits = 6 * E;
    const size_t off_msb  = 8 * E;
    const size_t off_minv = 8 * E + 524288;
    const size_t off_outp = 8 * E + 786432;
    const size_t need     = 16 * E + 786432;            // ~67.9 MB

    if (ws_size >= need) {
        char* ws = (char*)d_ws;
        __bf16* qb = (__bf16*)(ws + off_qb);
        __bf16* kb = (__bf16*)(ws + off_kb);
        __bf16* vt = (__bf16*)(ws + off_vt);
        unsigned short* bits = (unsigned short*)(ws + off_bits);
        float* msb  = (float*)(ws + off_msb);
        float* minv = (float*)(ws + off_minv);
        float* outp = (float*)(ws + off_outp);

        conv_qk<<<dim3((unsigned)(E / 8 / 256)), dim3(256), 0, stream>>>(q, k, qb, kb);
        conv_vt<<<dim3(NB * 16), dim3(256), 0, stream>>>(v, vt);
        kA_ms<<<dim3(1024), dim3(256), 0, stream>>>(qb, kb, mk, bits, msb);
        kM_merge<<<dim3(NB * NS / 256), dim3(256), 0, stream>>>(msb, minv, p);
        kB_pv<<<dim3(1024), dim3(256), 0, stream>>>(qb, kb, vt, bits, minv, p, outp);
        kC_add<<<dim3((unsigned)(E / 4 / 256)), dim3(256), 0, stream>>>(outp, out);
    } else {
        qa_fused_fb<<<dim3(NB * (NS / 64)), dim3(256), 0, stream>>>(q, k, v, mk, out, p);
    }
}